// Round 6
// baseline (516.943 us; speedup 1.0000x reference)
//
#include <hip/hip_runtime.h>
#include <hip/hip_bf16.h>

#define NPTS 200000
#define INC  64
#define OUTC 128
#define KTAP 27
#define EPSV 1e-5f
#define BM   64
#define NSHADOW 32

typedef __attribute__((ext_vector_type(8))) short bf16x8;
typedef __attribute__((ext_vector_type(4))) float f32x4;

__device__ __forceinline__ unsigned short f2bf(float f) {
  unsigned int u = __float_as_uint(f);
  return (unsigned short)((u + 0x7FFFu + ((u >> 16) & 1u)) >> 16);
}

// Transposed (unswizzled) bf16 weight image: per-tap 16KB block,
// byte for (c,i) = c*128 + 2*i.
__global__ void prep_weight(const float* __restrict__ w, unsigned char* __restrict__ img) {
  int kn = blockIdx.x;
  const float* wk = w + kn * (INC * OUTC);
  unsigned char* dst = img + kn * (INC * OUTC * 2);
  for (int e = threadIdx.x; e < INC * OUTC; e += blockDim.x) {
    int c = e >> 6;
    int i = e & 63;
    unsigned short h = f2bf(wk[i * OUTC + c]);
    *(unsigned short*)(dst + c * 128 + i * 2) = h;
  }
}

// feats fp32 (N x 64) -> bf16 rows of 128B.
__global__ __launch_bounds__(256) void prep_feats(const float* __restrict__ f,
                                                  unsigned short* __restrict__ o) {
  size_t i = (size_t)blockIdx.x * 256 + threadIdx.x;
  float4 a = ((const float4*)f)[i * 2];
  float4 b = ((const float4*)f)[i * 2 + 1];
  ushort4 ha = make_ushort4(f2bf(a.x), f2bf(a.y), f2bf(a.z), f2bf(a.w));
  ushort4 hb = make_ushort4(f2bf(b.x), f2bf(b.y), f2bf(b.z), f2bf(b.w));
  ((ushort4*)o)[i * 2]     = ha;
  ((ushort4*)o)[i * 2 + 1] = hb;
}

// MODE 0 = full; 1 = no feature gathers (VALU splat); 2 = no B loads (const).
template<int MODE>
__global__ __launch_bounds__(256, 4) void conv_main(
    const unsigned short* __restrict__ fbf,
    const int*   __restrict__ nmap,
    const unsigned char* __restrict__ wimg,
    float* __restrict__ out,
    float* __restrict__ shadow)
{
  __shared__ __align__(16) unsigned char ldsA[2][BM * 128];

  const int t    = threadIdx.x;
  const int lane = t & 63;
  const int w    = t >> 6;
  const int n0   = blockIdx.x * BM;
  const int lr   = lane & 15;
  const int lg   = lane >> 4;
  const int row_ = t >> 3;
  const int c8_  = t & 7;

  f32x4 zv = {0.f, 0.f, 0.f, 0.f};
  f32x4 acc[4][2];
  #pragma unroll
  for (int i = 0; i < 4; ++i) { acc[i][0] = zv; acc[i][1] = zv; }

  const int na = n0 + row_;
  const int nb = na + 32;
  const unsigned wsw = ((unsigned)(row_ & 7)) << 4;

  // clamped masked gather: unconditional load (invalid -> hot row 0), cndmask zero
  auto gat = [&](int g) -> bf16x8 {
    if (MODE == 1) return (bf16x8)(short)g;
    int gc = (g >= 0) ? g : 0;
    bf16x8 v = *(const bf16x8*)(fbf + (size_t)gc * 64 + c8_ * 8);
    return (g >= 0) ? v : (bf16x8)(short)0;
  };

  bf16x8 v0a, v0b, v1a, v1b;
  int i2a, i2b, i3a, i3b;
  bf16x8 B0[4], B1[4];
  {
    int ia0 = nmap[na],        ib0 = nmap[nb];
    int ia1 = nmap[NPTS + na], ib1 = nmap[NPTS + nb];
    v0a = gat(ia0); v0b = gat(ib0);
    v1a = gat(ia1); v1b = gat(ib1);
    i2a = nmap[2 * NPTS + na]; i2b = nmap[2 * NPTS + nb];
    i3a = nmap[3 * NPTS + na]; i3b = nmap[3 * NPTS + nb];
    if (MODE == 2) {
      #pragma unroll
      for (int j = 0; j < 4; ++j) { B0[j] = (bf16x8)(short)0x3F80; B1[j] = (bf16x8)(short)0x3F80; }
    } else {
      #pragma unroll
      for (int kk = 0; kk < 2; ++kk)
        #pragma unroll
        for (int nf = 0; nf < 2; ++nf) {
          int c = w * 32 + nf * 16 + lr;
          B0[kk * 2 + nf] = *(const bf16x8*)(wimg + c * 128 + kk * 64 + lg * 16);
          B1[kk * 2 + nf] = *(const bf16x8*)(wimg + 16384 + c * 128 + kk * 64 + lg * 16);
        }
    }
  }

  auto tap = [&](int kn, unsigned char* buf, bf16x8& va, bf16x8& vb,
                 int& ia, int& ib, bf16x8* Bc) {
    unsigned int b0 = ((unsigned)(row_ * 128 + c8_ * 16)) ^ wsw;
    unsigned int b1 = ((unsigned)((row_ + 32) * 128 + c8_ * 16)) ^ wsw;
    *(bf16x8*)(buf + b0) = va;
    *(bf16x8*)(buf + b1) = vb;
    asm volatile("s_waitcnt lgkmcnt(0)" ::: "memory");
    __builtin_amdgcn_s_barrier();

    if (kn + 2 < KTAP) { va = gat(ia); vb = gat(ib); }
    if (kn + 4 < KTAP) {
      ia = nmap[(kn + 4) * NPTS + na];
      ib = nmap[(kn + 4) * NPTS + nb];
    }

    #pragma unroll
    for (int kk = 0; kk < 2; ++kk) {
      const int kb = kk * 64 + lg * 16;
      bf16x8 av[4];
      #pragma unroll
      for (int mf = 0; mf < 4; ++mf) {
        int row = mf * 16 + lr;
        unsigned int byte = ((unsigned)(row * 128 + kb)) ^ (((unsigned)(row & 7)) << 4);
        av[mf] = *(const bf16x8*)(buf + byte);
      }
      #pragma unroll
      for (int mf = 0; mf < 4; ++mf)
        #pragma unroll
        for (int nf = 0; nf < 2; ++nf)
          acc[mf][nf] = __builtin_amdgcn_mfma_f32_16x16x32_bf16(av[mf], Bc[kk * 2 + nf], acc[mf][nf], 0, 0, 0);
    }

    if (MODE != 2 && kn + 2 < KTAP) {
      const unsigned char* wb2 = wimg + (kn + 2) * 16384;
      #pragma unroll
      for (int kk = 0; kk < 2; ++kk)
        #pragma unroll
        for (int nf = 0; nf < 2; ++nf) {
          int c = w * 32 + nf * 16 + lr;
          Bc[kk * 2 + nf] = *(const bf16x8*)(wb2 + c * 128 + kk * 64 + lg * 16);
        }
    }
  };

  #pragma unroll 1
  for (int kn = 0; kn < KTAP - 1; kn += 2) {
    tap(kn,     ldsA[0], v0a, v0b, i2a, i2b, B0);
    tap(kn + 1, ldsA[1], v1a, v1b, i3a, i3b, B1);
  }
  tap(KTAP - 1, ldsA[0], v0a, v0b, i2a, i2b, B0);

  float* myshadow = shadow + (blockIdx.x & (NSHADOW - 1)) * 256;
  #pragma unroll
  for (int nf = 0; nf < 2; ++nf) {
    int c = w * 32 + nf * 16 + lr;
    float s = 0.f, s2 = 0.f;
    #pragma unroll
    for (int mf = 0; mf < 4; ++mf) {
      #pragma unroll
      for (int r = 0; r < 4; ++r) {
        float v = acc[mf][nf][r];
        s += v; s2 += v * v;
        int n = n0 + mf * 16 + lg * 4 + r;
        out[(size_t)n * OUTC + c] = v;
      }
    }
    s  += __shfl_xor(s, 16);  s  += __shfl_xor(s, 32);
    s2 += __shfl_xor(s2, 16); s2 += __shfl_xor(s2, 32);
    if (lane < 16) {
      atomicAdd(&myshadow[c], s);
      atomicAdd(&myshadow[128 + c], s2);
    }
  }
}

__global__ void finalize_stats(const float* __restrict__ shadow,
                               const float* __restrict__ gamma,
                               const float* __restrict__ beta,
                               float* __restrict__ scale,
                               float* __restrict__ shift) {
  __shared__ float accs[256];
  int t = threadIdx.x;
  float s = 0.f;
  for (int b = 0; b < NSHADOW; ++b) s += shadow[b * 256 + t];
  accs[t] = s;
  __syncthreads();
  if (t < OUTC) {
    float mean = accs[t] * (1.0f / (float)NPTS);
    float var  = accs[128 + t] * (1.0f / (float)NPTS) - mean * mean;
    var = fmaxf(var, 0.f);
    float sc = gamma[t] * rsqrtf(var + EPSV);
    scale[t] = sc;
    shift[t] = beta[t] - mean * sc;
  }
}

__global__ __launch_bounds__(256) void norm_relu(float* __restrict__ out,
                                                 const float* __restrict__ scale,
                                                 const float* __restrict__ shift) {
  __shared__ float s_sc[OUTC], s_sh[OUTC];
  if (threadIdx.x < OUTC) {
    s_sc[threadIdx.x] = scale[threadIdx.x];
    s_sh[threadIdx.x] = shift[threadIdx.x];
  }
  __syncthreads();
  const long total = (long)NPTS * OUTC / 4;
  for (long i = (long)blockIdx.x * blockDim.x + threadIdx.x; i < total;
       i += (long)gridDim.x * blockDim.x) {
    float4 v = ((float4*)out)[i];
    int cb = (int)(i & 31) * 4;
    v.x = fmaxf(v.x * s_sc[cb + 0] + s_sh[cb + 0], 0.f);
    v.y = fmaxf(v.y * s_sc[cb + 1] + s_sh[cb + 1], 0.f);
    v.z = fmaxf(v.z * s_sc[cb + 2] + s_sh[cb + 2], 0.f);
    v.w = fmaxf(v.w * s_sc[cb + 3] + s_sh[cb + 3], 0.f);
    ((float4*)out)[i] = v;
  }
}

extern "C" void kernel_launch(void* const* d_in, const int* in_sizes, int n_in,
                              void* d_out, int out_size, void* d_ws, size_t ws_size,
                              hipStream_t stream) {
  (void)in_sizes; (void)n_in; (void)out_size; (void)ws_size;
  const float* feats  = (const float*)d_in[0];
  const float* weight = (const float*)d_in[1];
  const float* gamma  = (const float*)d_in[2];
  const float* beta   = (const float*)d_in[3];
  const int*   nmap   = (const int*)d_in[4];
  float* out = (float*)d_out;

  unsigned char* ws = (unsigned char*)d_ws;
  const size_t FBF_BYTES  = (size_t)NPTS * 64 * 2;     // 25,600,000
  const size_t WIMG_BYTES = (size_t)KTAP * 16384;      // 442,368
  unsigned short* fbf = (unsigned short*)ws;
  unsigned char* wimg = ws + FBF_BYTES;
  float* shadow  = (float*)(ws + FBF_BYTES + WIMG_BYTES);  // 32*256
  float* scale   = shadow + NSHADOW * 256;
  float* shift   = scale + 128;
  float* shadow2 = shift + 128;                            // ablation sink, 32*256

  hipMemsetAsync(shadow, 0, NSHADOW * 256 * sizeof(float), stream);
  prep_weight<<<KTAP, 256, 0, stream>>>(weight, wimg);
  prep_feats<<<6250, 256, 0, stream>>>(feats, fbf);
  int grid = NPTS / BM;  // 3125
  // ---- ablation dispatches (out fully overwritten by V0 below) ----
  conv_main<1><<<grid, 256, 0, stream>>>(fbf, nmap, wimg, out, shadow2);
  conv_main<2><<<grid, 256, 0, stream>>>(fbf, nmap, wimg, out, shadow2);
  // ---- the real one ----
  conv_main<0><<<grid, 256, 0, stream>>>(fbf, nmap, wimg, out, shadow);
  finalize_stats<<<1, 256, 0, stream>>>(shadow, gamma, beta, scale, shift);
  norm_relu<<<4096, 256, 0, stream>>>(out, scale, shift);
}

// Round 7
// 195.061 us; speedup vs baseline: 2.6502x; 2.6502x over previous
//
#include <hip/hip_runtime.h>
#include <hip/hip_bf16.h>

#define NPTS 200000
#define INC  64
#define OUTC 128
#define KTAP 27
#define EPSV 1e-5f
#define BM   128
#define NSHADOW 32

typedef __attribute__((ext_vector_type(8))) short bf16x8;
typedef __attribute__((ext_vector_type(4))) float f32x4;

__device__ __forceinline__ unsigned short f2bf(float f) {
  unsigned int u = __float_as_uint(f);
  return (unsigned short)((u + 0x7FFFu + ((u >> 16) & 1u)) >> 16);
}

// Transposed (linear) bf16 weight image: per-tap 16KB block, byte(c,i) = c*128 + 2*i.
__global__ void prep_weight(const float* __restrict__ w, unsigned char* __restrict__ img) {
  int kn = blockIdx.x;
  const float* wk = w + kn * (INC * OUTC);
  unsigned char* dst = img + kn * (INC * OUTC * 2);
  for (int e = threadIdx.x; e < INC * OUTC; e += blockDim.x) {
    int c = e >> 6;
    int i = e & 63;
    unsigned short h = f2bf(wk[i * OUTC + c]);
    *(unsigned short*)(dst + c * 128 + i * 2) = h;
  }
}

// feats fp32 (N x 64) -> bf16 rows of 128B.
__global__ __launch_bounds__(256) void prep_feats(const float* __restrict__ f,
                                                  unsigned short* __restrict__ o) {
  size_t i = (size_t)blockIdx.x * 256 + threadIdx.x;
  float4 a = ((const float4*)f)[i * 2];
  float4 b = ((const float4*)f)[i * 2 + 1];
  ushort4 ha = make_ushort4(f2bf(a.x), f2bf(a.y), f2bf(a.z), f2bf(a.w));
  ushort4 hb = make_ushort4(f2bf(b.x), f2bf(b.y), f2bf(b.z), f2bf(b.w));
  ((ushort4*)o)[i * 2]     = ha;
  ((ushort4*)o)[i * 2 + 1] = hb;
}

__global__ __launch_bounds__(512, 4) void conv_main(
    const unsigned short* __restrict__ fbf,
    const int*   __restrict__ nmap,
    const unsigned char* __restrict__ wimg,
    float* __restrict__ out,
    float* __restrict__ shadow)
{
  __shared__ __align__(16) unsigned char ldsA[2][BM * 128];    // 2 x 16KB
  __shared__ __align__(16) unsigned char ldsB[2][OUTC * 128];  // 2 x 16KB

  const int t    = threadIdx.x;
  const int lane = t & 63;
  const int w    = t >> 6;        // 0..7
  const int wm   = w >> 2;        // 0..1 : row half (64 rows)
  const int wn   = w & 3;         // 0..3 : col quarter (32 cols)
  const int n0   = blockIdx.x * BM;
  const int lr   = lane & 15;
  const int lg   = lane >> 4;
  const int srow = t >> 2;        // 0..127 staging row / col
  const int sch  = t & 3;         // 32B chunk within 128B row
  const unsigned swz = ((unsigned)(srow & 7)) << 4;

  const int n_st = n0 + srow;
  const int n_cl = (n_st < NPTS) ? n_st : (NPTS - 1);
  const bool rowok = (n_st < NPTS);

  f32x4 zv = {0.f, 0.f, 0.f, 0.f};
  f32x4 acc[4][2];
  #pragma unroll
  for (int i = 0; i < 4; ++i) { acc[i][0] = zv; acc[i][1] = zv; }

  auto ldidx = [&](int k) -> int {
    int raw = nmap[(size_t)k * NPTS + n_cl];
    return rowok ? raw : -1;
  };
  // clamped masked gather of one row's 32B chunk (2 x bf16x8)
  auto gat = [&](int g, bf16x8& a, bf16x8& b) {
    int gc = (g >= 0) ? g : 0;
    const bf16x8* p = (const bf16x8*)(fbf + (size_t)gc * 64 + sch * 16);
    bf16x8 x = p[0], y = p[1];
    a = (g >= 0) ? x : (bf16x8)(short)0;
    b = (g >= 0) ? y : (bf16x8)(short)0;
  };
  auto ldB = [&](int k, bf16x8& a, bf16x8& b) {
    const bf16x8* p = (const bf16x8*)(wimg + (size_t)k * 16384 + t * 32);
    a = p[0]; b = p[1];
  };

  // ---- prologue ----
  bf16x8 vA0a, vA0b, vA1a, vA1b, vB0, vB1;
  int iA, iB;
  {
    int i0 = ldidx(0), i1 = ldidx(1);
    gat(i0, vA0a, vA0b);
    gat(i1, vA1a, vA1b);
    iA = ldidx(2); iB = ldidx(3);
    ldB(0, vB0, vB1);
  }

  const unsigned bst = ((unsigned)(srow * 128 + sch * 32)) ^ swz;

  auto tap = [&](int kn, int bsel, bf16x8& va, bf16x8& vb, int& inx,
                 bool doG, bool doB) {
    // stage A(kn), B(kn) from regs (swizzled)
    *(bf16x8*)(ldsA[bsel] + bst) = va;
    *(bf16x8*)(ldsA[bsel] + (bst ^ 16u)) = vb;
    *(bf16x8*)(ldsB[bsel] + bst) = vB0;
    *(bf16x8*)(ldsB[bsel] + (bst ^ 16u)) = vB1;
    asm volatile("s_waitcnt lgkmcnt(0)" ::: "memory");
    __builtin_amdgcn_s_barrier();

    // issue next loads (latency hides under compute + next tap)
    if (doG) gat(inx, va, vb);            // data for tap kn+2
    if (kn + 4 < KTAP) inx = ldidx(kn + 4);
    if (doB) ldB(kn + 1, vB0, vB1);       // B for tap kn+1

    // compute tap kn
    #pragma unroll
    for (int kk = 0; kk < 2; ++kk) {
      const int kb = kk * 64 + lg * 16;
      bf16x8 av[4], bv[2];
      #pragma unroll
      for (int mf = 0; mf < 4; ++mf) {
        int row = wm * 64 + mf * 16 + lr;
        unsigned byte = ((unsigned)(row * 128 + kb)) ^ (((unsigned)(row & 7)) << 4);
        av[mf] = *(const bf16x8*)(ldsA[bsel] + byte);
      }
      #pragma unroll
      for (int nf = 0; nf < 2; ++nf) {
        int col = wn * 32 + nf * 16 + lr;
        unsigned byte = ((unsigned)(col * 128 + kb)) ^ (((unsigned)(col & 7)) << 4);
        bv[nf] = *(const bf16x8*)(ldsB[bsel] + byte);
      }
      #pragma unroll
      for (int mf = 0; mf < 4; ++mf)
        #pragma unroll
        for (int nf = 0; nf < 2; ++nf)
          acc[mf][nf] = __builtin_amdgcn_mfma_f32_16x16x32_bf16(av[mf], bv[nf], acc[mf][nf], 0, 0, 0);
    }
  };

  #pragma unroll 1
  for (int kn = 0; kn < KTAP - 1; kn += 2) {
    tap(kn,     0, vA0a, vA0b, iA, kn + 2 < KTAP, true);
    tap(kn + 1, 1, vA1a, vA1b, iB, kn + 3 < KTAP, true);
  }
  tap(KTAP - 1, 0, vA0a, vA0b, iA, false, false);

  // ---- epilogue: stores + wave-reduced channel sums -> 32-shadow atomics ----
  float* myshadow = shadow + (blockIdx.x & (NSHADOW - 1)) * 256;
  #pragma unroll
  for (int nf = 0; nf < 2; ++nf) {
    int c = wn * 32 + nf * 16 + lr;
    float s = 0.f, s2 = 0.f;
    #pragma unroll
    for (int mf = 0; mf < 4; ++mf) {
      #pragma unroll
      for (int r = 0; r < 4; ++r) {
        float v = acc[mf][nf][r];
        int n = n0 + wm * 64 + mf * 16 + lg * 4 + r;
        if (n < NPTS) {
          s += v; s2 += v * v;
          out[(size_t)n * OUTC + c] = v;
        }
      }
    }
    s  += __shfl_xor(s, 16);  s  += __shfl_xor(s, 32);
    s2 += __shfl_xor(s2, 16); s2 += __shfl_xor(s2, 32);
    if (lane < 16) {
      atomicAdd(&myshadow[c], s);
      atomicAdd(&myshadow[128 + c], s2);
    }
  }
}

__global__ void finalize_stats(const float* __restrict__ shadow,
                               const float* __restrict__ gamma,
                               const float* __restrict__ beta,
                               float* __restrict__ scale,
                               float* __restrict__ shift) {
  __shared__ float accs[256];
  int t = threadIdx.x;
  float s = 0.f;
  for (int b = 0; b < NSHADOW; ++b) s += shadow[b * 256 + t];
  accs[t] = s;
  __syncthreads();
  if (t < OUTC) {
    float mean = accs[t] * (1.0f / (float)NPTS);
    float var  = accs[128 + t] * (1.0f / (float)NPTS) - mean * mean;
    var = fmaxf(var, 0.f);
    float sc = gamma[t] * rsqrtf(var + EPSV);
    scale[t] = sc;
    shift[t] = beta[t] - mean * sc;
  }
}

__global__ __launch_bounds__(256) void norm_relu(float* __restrict__ out,
                                                 const float* __restrict__ scale,
                                                 const float* __restrict__ shift) {
  __shared__ float s_sc[OUTC], s_sh[OUTC];
  if (threadIdx.x < OUTC) {
    s_sc[threadIdx.x] = scale[threadIdx.x];
    s_sh[threadIdx.x] = shift[threadIdx.x];
  }
  __syncthreads();
  const long total = (long)NPTS * OUTC / 4;
  for (long i = (long)blockIdx.x * blockDim.x + threadIdx.x; i < total;
       i += (long)gridDim.x * blockDim.x) {
    float4 v = ((float4*)out)[i];
    int cb = (int)(i & 31) * 4;
    v.x = fmaxf(v.x * s_sc[cb + 0] + s_sh[cb + 0], 0.f);
    v.y = fmaxf(v.y * s_sc[cb + 1] + s_sh[cb + 1], 0.f);
    v.z = fmaxf(v.z * s_sc[cb + 2] + s_sh[cb + 2], 0.f);
    v.w = fmaxf(v.w * s_sc[cb + 3] + s_sh[cb + 3], 0.f);
    ((float4*)out)[i] = v;
  }
}

extern "C" void kernel_launch(void* const* d_in, const int* in_sizes, int n_in,
                              void* d_out, int out_size, void* d_ws, size_t ws_size,
                              hipStream_t stream) {
  (void)in_sizes; (void)n_in; (void)out_size; (void)ws_size;
  const float* feats  = (const float*)d_in[0];
  const float* weight = (const float*)d_in[1];
  const float* gamma  = (const float*)d_in[2];
  const float* beta   = (const float*)d_in[3];
  const int*   nmap   = (const int*)d_in[4];
  float* out = (float*)d_out;

  unsigned char* ws = (unsigned char*)d_ws;
  const size_t FBF_BYTES  = (size_t)NPTS * 64 * 2;     // 25,600,000
  const size_t WIMG_BYTES = (size_t)KTAP * 16384;      // 442,368
  unsigned short* fbf = (unsigned short*)ws;
  unsigned char* wimg = ws + FBF_BYTES;
  float* shadow = (float*)(ws + FBF_BYTES + WIMG_BYTES);  // 32*256
  float* scale  = shadow + NSHADOW * 256;
  float* shift  = scale + 128;

  hipMemsetAsync(shadow, 0, NSHADOW * 256 * sizeof(float), stream);
  prep_weight<<<KTAP, 256, 0, stream>>>(weight, wimg);
  prep_feats<<<6250, 256, 0, stream>>>(feats, fbf);
  int grid = (NPTS + BM - 1) / BM;  // 1563
  conv_main<<<grid, 512, 0, stream>>>(fbf, nmap, wimg, out, shadow);
  finalize_stats<<<1, 256, 0, stream>>>(shadow, gamma, beta, scale, shift);
  norm_relu<<<4096, 256, 0, stream>>>(out, scale, shift);
}